// Round 2
// baseline (75.973 us; speedup 1.0000x reference)
//
#include <hip/hip_runtime.h>

#define NG 512
#define IMG_H 192
#define IMG_W 192
#define NPIX (IMG_H * IMG_W)
#define GF 12            // floats per record: u,v,A,B,C,op,beta,r,g,b,pad,pad
#define TILE_W 64
#define TILE_H 8
#define GX (IMG_W / TILE_W)   // 3
#define GY (IMG_H / TILE_H)   // 24  -> 72 blocks

// Single fused kernel. Grid = 72 blocks x 512 threads.
// Thread t owns gaussian t (projection math, in registers) AND pixel
// (x0 + (t&63), y0 + (t>>6)) of the block's 64x8 tile.
// Phases: project -> exact tile cull -> ballot-compact survivors ->
// rank only the m survivors by strict (depth,idx) key -> scatter sorted
// records to LDS -> per-pixel front-to-back composite. No workspace use.
__global__ __launch_bounds__(512) void splat_fused(
    const float* __restrict__ means, const float* __restrict__ quats,
    const float* __restrict__ scales, const float* __restrict__ opac,
    const float* __restrict__ colors, const float* __restrict__ betas,
    const float* __restrict__ vm, const float* __restrict__ Ks,
    float* __restrict__ out)
{
    __shared__ __align__(16) float gs[NG * GF];            // sorted survivor records (24 KB)
    __shared__ unsigned long long skey[NG];                // survivor keys (4 KB)
    __shared__ int wcnt[8];
    __shared__ int woff[9];

    const int tid  = threadIdx.x;
    const int lane = tid & 63;
    const int wv   = tid >> 6;          // wave id == tile row 0..7

    const int bx = blockIdx.x % GX;
    const int by = blockIdx.x / GX;
    const int x0 = bx * TILE_W;
    const int y0 = by * TILE_H;

    // ---- issue ALL global loads for the owned gaussian up front ----
    const float mx = means[tid*3+0], my = means[tid*3+1], mz = means[tid*3+2];
    const float4 q4 = *(const float4*)(quats + tid*4);
    const float s0 = scales[tid*3+0], s1 = scales[tid*3+1], s2 = scales[tid*3+2];
    const float opraw = opac[tid];
    const float col0 = colors[tid*3+0], col1 = colors[tid*3+1], col2 = colors[tid*3+2];
    const float bt = betas[tid];

    const float Rw00=vm[0], Rw01=vm[1], Rw02=vm[2],  tw0=vm[3];
    const float Rw10=vm[4], Rw11=vm[5], Rw12=vm[6],  tw1=vm[7];
    const float Rw20=vm[8], Rw21=vm[9], Rw22=vm[10], tw2=vm[11];
    const float fx=Ks[0], cx=Ks[2], fy=Ks[4], cy=Ks[5];

    // ---- view-space position ----
    const float px_ = Rw00*mx + Rw01*my + Rw02*mz + tw0;
    const float py_ = Rw10*mx + Rw11*my + Rw12*mz + tw1;
    const float pz  = Rw20*mx + Rw21*my + Rw22*mz + tw2;

    // strict total-order depth key: (float-order(pz), idx) packed into u64.
    // Ties in pz break by index -> matches jnp.argsort's stable order.
    unsigned int ub = __float_as_uint(pz);
    ub = (pz < 0.0f) ? ~ub : (ub | 0x80000000u);
    const unsigned long long kd = ((unsigned long long)ub << 32) | (unsigned int)tid;

    // ---- projection math (identical formulas to the verified 2-kernel version) ----
    float qw = q4.x, qx = q4.y, qy = q4.z, qz = q4.w;
    const float qn = 1.0f / sqrtf(qw*qw + qx*qx + qy*qy + qz*qz);
    qw *= qn; qx *= qn; qy *= qn; qz *= qn;
    float Rq[3][3];
    Rq[0][0] = 1.f - 2.f*(qy*qy + qz*qz); Rq[0][1] = 2.f*(qx*qy - qw*qz); Rq[0][2] = 2.f*(qx*qz + qw*qy);
    Rq[1][0] = 2.f*(qx*qy + qw*qz); Rq[1][1] = 1.f - 2.f*(qx*qx + qz*qz); Rq[1][2] = 2.f*(qy*qz - qw*qx);
    Rq[2][0] = 2.f*(qx*qz - qw*qy); Rq[2][1] = 2.f*(qy*qz + qw*qx); Rq[2][2] = 1.f - 2.f*(qx*qx + qy*qy);

    const float e0 = expf(s0), e1 = expf(s1), e2 = expf(s2);

    float M[3][3];
    #pragma unroll
    for (int i = 0; i < 3; i++) { M[i][0] = Rq[i][0]*e0; M[i][1] = Rq[i][1]*e1; M[i][2] = Rq[i][2]*e2; }
    float c3[3][3];
    #pragma unroll
    for (int i = 0; i < 3; i++)
        #pragma unroll
        for (int k = 0; k < 3; k++)
            c3[i][k] = M[i][0]*M[k][0] + M[i][1]*M[k][1] + M[i][2]*M[k][2];

    const float Rw[3][3] = {{Rw00,Rw01,Rw02},{Rw10,Rw11,Rw12},{Rw20,Rw21,Rw22}};
    float tmpm[3][3];
    #pragma unroll
    for (int i = 0; i < 3; i++)
        #pragma unroll
        for (int k = 0; k < 3; k++)
            tmpm[i][k] = Rw[i][0]*c3[0][k] + Rw[i][1]*c3[1][k] + Rw[i][2]*c3[2][k];
    float S[3][3];
    #pragma unroll
    for (int i = 0; i < 3; i++)
        #pragma unroll
        for (int l = 0; l < 3; l++)
            S[i][l] = tmpm[i][0]*Rw[l][0] + tmpm[i][1]*Rw[l][1] + tmpm[i][2]*Rw[l][2];

    const float tz = fmaxf(pz, 0.01f);
    const float z1 = 1.0f / tz;
    const float j0 = fx*z1, j2 = -fx*px_*z1*z1;
    const float j1 = fy*z1, j3 = -fy*py_*z1*z1;

    const float cov00 = j0*j0*S[0][0] + 2.f*j0*j2*S[0][2] + j2*j2*S[2][2];
    const float cov01 = j0*j1*S[0][1] + j0*j3*S[0][2] + j2*j1*S[1][2] + j2*j3*S[2][2];
    const float cov11 = j1*j1*S[1][1] + 2.f*j1*j3*S[1][2] + j3*j3*S[2][2];

    const float a = cov00 + 0.3f;
    const float b = cov01;
    const float c = cov11 + 0.3f;
    const float det = a*c - b*b;
    const float uu = fx*px_*z1 + cx;
    const float vv = fy*py_*z1 + cy;
    const bool valid = (pz > 0.01f) && (det > 1e-6f);
    const float inv_det = 1.0f / fmaxf(det, 1e-6f);
    const float Ac = c * inv_det;       // > 0 always (c >= 0.3, inv_det > 0)
    const float Bc = -b * inv_det;
    const float Cc = a * inv_det;       // > 0 always
    float op = 1.0f / (1.0f + expf(-opraw));
    if (!valid) op = 0.0f;              // zero opacity == culled everywhere

    // ---- exact min of the positive-definite quadratic over the tile rectangle ----
    // Center inside the box -> min 0; otherwise min lies on one of the 4 edges:
    // evaluate each edge's clamped 1-D minimizer, take the min. Continuous min
    // <= min over pixel centers, so the cull is strictly conservative.
    const float xlo = (float)x0 + 0.5f, xhi = (float)x0 + (float)TILE_W - 0.5f;
    const float ylo = (float)y0 + 0.5f, yhi = (float)y0 + (float)TILE_H - 0.5f;
    const float dxl = xlo - uu, dxh = xhi - uu;
    const float dyl = ylo - vv, dyh = yhi - vv;
    float smin = 0.0f;
    if (!(dxl <= 0.0f && dxh >= 0.0f && dyl <= 0.0f && dyh >= 0.0f)) {
        const float rA = 1.0f / Ac, rC = 1.0f / Cc;
        float dxs, dys;
        dxs = fminf(fmaxf(-Bc*dyl*rA, dxl), dxh);
        const float s1e = 0.5f*(Ac*dxs*dxs + Cc*dyl*dyl) + Bc*dxs*dyl;
        dxs = fminf(fmaxf(-Bc*dyh*rA, dxl), dxh);
        const float s2e = 0.5f*(Ac*dxs*dxs + Cc*dyh*dyh) + Bc*dxs*dyh;
        dys = fminf(fmaxf(-Bc*dxl*rC, dyl), dyh);
        const float s3e = 0.5f*(Ac*dxl*dxl + Cc*dys*dys) + Bc*dxl*dys;
        dys = fminf(fmaxf(-Bc*dxh*rC, dyl), dyh);
        const float s4e = 0.5f*(Ac*dxh*dxh + Cc*dys*dys) + Bc*dxh*dys;
        smin = fmaxf(fminf(fminf(s1e, s2e), fminf(s3e, s4e)), 0.0f);
    }
    const float smc  = fmaxf(smin, 1e-8f);
    const float sem  = (bt == 1.0f) ? smc : powf(smc, bt);
    const float amax = op * expf(-sem);
    const bool keep  = amax > (1.0f / 255.0f);

    // ---- ballot-compact survivors (arbitrary order), publish keys ----
    const unsigned long long bal = __ballot(keep);
    if (lane == 0) wcnt[wv] = __popcll(bal);
    __syncthreads();
    if (tid == 0) {
        int sacc = 0;
        #pragma unroll
        for (int k = 0; k < 8; k++) { woff[k] = sacc; sacc += wcnt[k]; }
        woff[8] = sacc;
    }
    __syncthreads();
    if (keep) {
        const int p = woff[wv] + __popcll(bal & ((1ULL << lane) - 1));
        skey[p] = kd;
    }
    __syncthreads();

    const int total = woff[8];

    // ---- rank only the survivors (m ~ 10-30 => m^2 compares per block),
    //      scatter depth-sorted records straight from registers ----
    if (keep) {
        int rs = 0;
        for (int j = 0; j < total; j++) rs += (skey[j] < kd) ? 1 : 0;
        float4* dst = (float4*)(gs + rs * GF);   // 48B stride keeps 16B alignment
        dst[0] = make_float4(uu, vv, Ac, Bc);
        dst[1] = make_float4(Cc, op, bt, col0);
        dst[2] = make_float4(col1, col2, 0.0f, 0.0f);
    }
    __syncthreads();

    // ---- per-pixel front-to-back composite (no chunk split, no combine wave) ----
    const float fxp = (float)(x0 + lane) + 0.5f;
    const float fyp = (float)(y0 + wv)  + 0.5f;
    float T = 1.0f, cr = 0.0f, cg = 0.0f, cb = 0.0f, acw = 0.0f;
    for (int i = 0; i < total; i++) {
        const float4 r0 = *(const float4*)(gs + i*GF);      // u,v,A,B   (uniform: broadcast)
        const float4 r1 = *(const float4*)(gs + i*GF + 4);  // C,op,bt,r
        const float2 r2 = *(const float2*)(gs + i*GF + 8);  // g,b
        const float dx = fxp - r0.x;
        const float dy = fyp - r0.y;
        float sigma = 0.5f*(r0.z*dx*dx + r1.x*dy*dy) + r0.w*dx*dy;
        sigma = fmaxf(sigma, 1e-8f);
        const float se = (r1.z == 1.0f) ? sigma : powf(sigma, r1.z);
        float alpha = r1.y * expf(-se);
        alpha = fminf(alpha, 0.999f);
        if (!(alpha > (1.0f / 255.0f))) alpha = 0.0f;
        const float w = alpha * T;
        cr += w * r1.w; cg += w * r2.x; cb += w * r2.y;
        acw += w;
        T *= 1.0f - alpha;
    }

    const int pix = (y0 + wv) * IMG_W + x0 + lane;
    out[pix*3 + 0] = cr;
    out[pix*3 + 1] = cg;
    out[pix*3 + 2] = cb;
    out[NPIX*3 + pix] = acw;
}

extern "C" void kernel_launch(void* const* d_in, const int* in_sizes, int n_in,
                              void* d_out, int out_size, void* d_ws, size_t ws_size,
                              hipStream_t stream) {
    (void)in_sizes; (void)n_in; (void)d_ws; (void)ws_size; (void)out_size;
    const float* means  = (const float*)d_in[0];
    const float* quats  = (const float*)d_in[1];
    const float* scales = (const float*)d_in[2];
    const float* opac   = (const float*)d_in[3];
    const float* colors = (const float*)d_in[4];
    const float* betas  = (const float*)d_in[5];
    const float* vm     = (const float*)d_in[6];
    const float* Ks     = (const float*)d_in[7];
    float* out = (float*)d_out;

    splat_fused<<<GX * GY, 512, 0, stream>>>(means, quats, scales, opac, colors, betas, vm, Ks, out);
}